// Round 7
// baseline (267.708 us; speedup 1.0000x reference)
//
#include <hip/hip_runtime.h>
#include <hip/hip_bf16.h>

#define M_TOTAL 16384
#define KDIM 2048
#define NDIM 2048
#define NEXP 8
#define BM 256
#define BN 128
#define BK 64
#define RT_MAX 71           // 16384/256 + 7 boundary extras
#define CT 16               // 2048/128 col tiles
#define NWG (RT_MAX * CT)   // 1136 = 8 * 142
#define BUFB 49152          // (256+128) rows x 128B per K-tile buffer

typedef __attribute__((ext_vector_type(8))) __bf16 bf16x8;
typedef __attribute__((ext_vector_type(4))) float f32x4;

__device__ inline int minI(int a, int b) { return a < b ? a : b; }

__device__ inline bf16x8 cvt8(float4 a, float4 b) {
  bf16x8 r;
  r[0] = (__bf16)a.x; r[1] = (__bf16)a.y; r[2] = (__bf16)a.z; r[3] = (__bf16)a.w;
  r[4] = (__bf16)b.x; r[5] = (__bf16)b.y; r[6] = (__bf16)b.z; r[7] = (__bf16)b.w;
  return r;
}

__device__ inline void gload16(const void* g, void* l) {
  __builtin_amdgcn_global_load_lds(
      (const __attribute__((address_space(1))) void*)g,
      (__attribute__((address_space(3))) void*)l, 16, 0, 0);
}

// ---------------- fp32 -> bf16 conversion (x then W) ----------------
__global__ __launch_bounds__(256) void cvt_both(
    const float* __restrict__ x, const float* __restrict__ w,
    bf16x8* __restrict__ xb, bf16x8* __restrict__ wb) {
  const int NX = (M_TOTAL * KDIM) / 8;
  const int NW = (NEXP * NDIM * KDIM) / 8;
  const int stride = gridDim.x * blockDim.x;
  for (int i = blockIdx.x * blockDim.x + threadIdx.x; i < NX + NW; i += stride) {
    const float4* src = (i < NX) ? ((const float4*)x + (size_t)i * 2)
                                 : ((const float4*)w + (size_t)(i - NX) * 2);
    float4 a = src[0], b = src[1];
    bf16x8 c = cvt8(a, b);
    if (i < NX) xb[i] = c; else wb[i - NX] = c;
  }
}

// ---------------- grouped GEMM: 256x128 tile, BK=64, 3 LDS buffers (144KB).
// 8 waves (4M x 2N) of 64x64. 2 phases per K-tile (ks0/ks1): 8 ds_read_b128 +
// 16 MFMA each. Tile t+2's full 6-unit stage goes into the IDLE buffer
// (t+2)%3 at tile t ph1 (buffer free since t-1 finished; barrier-ordered).
// Single vmcnt(6) per tile waits for loads issued 3 phases (~750+cyc) earlier
// -> covers L3 latency, no per-phase stall. Swizzle: phys chunk = c ^ (row&7),
// applied via pre-swizzled per-lane global source (LDS dest stays linear).
__global__ __launch_bounds__(512, 2) void moe_gemm_d3(
    const __hip_bfloat16* __restrict__ xb, const __hip_bfloat16* __restrict__ wb,
    const int* __restrict__ ms, float* __restrict__ out) {
  __shared__ __align__(16) char lds[3 * BUFB];

  // bijective XCD swizzle (NWG = 1136 = 8*142)
  const int orig = blockIdx.x;
  const int wg = (orig & 7) * (NWG / 8) + (orig >> 3);
  const int bt = wg >> 4;     // row-tile 0..70
  const int ntile = wg & 15;  // col-tile 0..15

  // ---- map bt -> (expert e, row0, rows) ----
  int sizes[NEXP];
#pragma unroll
  for (int i = 0; i < NEXP; ++i) sizes[i] = ms[i];
  int e = 0, row0 = 0, rows = 0, acc_t = 0, start = 0;
  bool found = false;
#pragma unroll
  for (int i = 0; i < NEXP; ++i) {
    int nt = (sizes[i] + BM - 1) >> 8;
    if (!found && bt < acc_t + nt) {
      found = true; e = i;
      int tt = bt - acc_t;
      row0 = start + tt * BM;
      rows = minI(sizes[i] - tt * BM, BM);
    }
    acc_t += nt; start += sizes[i];
  }
  if (!found) return;

  const int tid = threadIdx.x;
  const int lane = tid & 63;
  const int wave = tid >> 6;
  const int wr = wave >> 1, wc = wave & 1;  // 4M x 2N waves, 64x64 out each
  const int col0 = ntile * BN;

  // ---- staging: 6 units of 8KB (64 rows x 128B); thread -> row tid>>3,
  // phys chunk tid&7; logical chunk = (tid&7)^(row&7) -> pre-swizzled col ----
  const int urow = tid >> 3;
  const int colel = (((tid & 7) ^ ((tid >> 3) & 7)) << 3);
  const __hip_bfloat16* wbase = wb + (size_t)e * NDIM * KDIM;
  const __hip_bfloat16* aU0 = xb + (size_t)minI(row0 +   0 + urow, M_TOTAL - 1) * KDIM + colel;
  const __hip_bfloat16* aU1 = xb + (size_t)minI(row0 +  64 + urow, M_TOTAL - 1) * KDIM + colel;
  const __hip_bfloat16* aU2 = xb + (size_t)minI(row0 + 128 + urow, M_TOTAL - 1) * KDIM + colel;
  const __hip_bfloat16* aU3 = xb + (size_t)minI(row0 + 192 + urow, M_TOTAL - 1) * KDIM + colel;
  const __hip_bfloat16* bU0 = wbase + (size_t)(col0 +  0 + urow) * KDIM + colel;
  const __hip_bfloat16* bU1 = wbase + (size_t)(col0 + 64 + urow) * KDIM + colel;

  // ---- fragment read lane terms (swizzled; phys = (ks*4+fc) ^ (fr&7)) ----
  const int fr = lane & 15, fc = lane >> 4;
  const int swz0 = fr * 128 + (((fc) ^ (fr & 7)) << 4);      // ks=0
  const int swz1 = fr * 128 + (((4 + fc) ^ (fr & 7)) << 4);  // ks=1
  const int aOff = wr * 8192;           // A rows wr*64.. within buffer
  const int bOff = 32768 + wc * 8192;   // B rows wc*64..

  f32x4 acc[4][4];
  const f32x4 zero = {0.f, 0.f, 0.f, 0.f};
#pragma unroll
  for (int i = 0; i < 4; ++i)
#pragma unroll
    for (int j = 0; j < 4; ++j) acc[i][j] = zero;

  bf16x8 af[4], bv[4];

#define ST6(D, T) { char* b_ = lds + (D) * BUFB + wave * 1024; \
    gload16(aU0 + (size_t)(T) * BK, b_); \
    gload16(aU1 + (size_t)(T) * BK, b_ + 8192); \
    gload16(aU2 + (size_t)(T) * BK, b_ + 16384); \
    gload16(aU3 + (size_t)(T) * BK, b_ + 24576); \
    gload16(bU0 + (size_t)(T) * BK, b_ + 32768); \
    gload16(bU1 + (size_t)(T) * BK, b_ + 40960); }
#define VM6 asm volatile("s_waitcnt vmcnt(6)" ::: "memory");
#define VM0 asm volatile("s_waitcnt vmcnt(0)" ::: "memory");

#define PH(D, SWZ, STBLK, WAITBLK) { \
    _Pragma("unroll") for (int mt = 0; mt < 4; ++mt) \
      af[mt] = *(const bf16x8*)(lds + (D) * BUFB + aOff + mt * 2048 + SWZ); \
    _Pragma("unroll") for (int nt = 0; nt < 4; ++nt) \
      bv[nt] = *(const bf16x8*)(lds + (D) * BUFB + bOff + nt * 2048 + SWZ); \
    STBLK \
    __builtin_amdgcn_s_barrier(); \
    asm volatile("s_waitcnt lgkmcnt(0)" ::: "memory"); \
    __builtin_amdgcn_s_setprio(1); \
    _Pragma("unroll") for (int mt = 0; mt < 4; ++mt) \
      _Pragma("unroll") for (int nt = 0; nt < 4; ++nt) \
        acc[mt][nt] = __builtin_amdgcn_mfma_f32_16x16x32_bf16( \
            af[mt], bv[nt], acc[mt][nt], 0, 0, 0); \
    __builtin_amdgcn_s_setprio(0); \
    WAITBLK \
    asm volatile("" ::: "memory"); \
    __builtin_amdgcn_s_barrier(); \
    asm volatile("" ::: "memory"); \
  }

// Tile t reading buffer D: ph1 stages t+2 -> idle buffer (D+2)%3; ph2 ends
// with vmcnt(6): waits tile t+1's 6 units (issued 3 phases earlier), leaves
// t+2's 6 in flight.
#define TILE(D, T, DOST, WB) { \
    PH(D, swz0, { if (DOST) ST6(((D) + 2) % 3, (T) + 2) }, {}) \
    PH(D, swz1, {}, WB) }

  // prologue: stage tiles 0,1 (12 units); wait tile 0, leave tile 1 in flight
  ST6(0, 0)
  ST6(1, 1)
  VM6
  __builtin_amdgcn_s_barrier();

  for (int i = 0; i < 10; ++i) {
    const int t = 3 * i;
    TILE(0, t,     true, VM6)
    TILE(1, t + 1, true, VM6)
    TILE(2, t + 2, true, VM6)
  }
  TILE(0, 30, false, VM0)   // drain tile 31's units
  TILE(1, 31, false, {})

#undef TILE
#undef PH
#undef VM0
#undef VM6
#undef ST6

  // ---- epilogue: C/D layout col=lane&15, row=(lane>>4)*4+j ----
  const int er = (lane >> 4) * 4;
#pragma unroll
  for (int mt = 0; mt < 4; ++mt) {
#pragma unroll
    for (int j = 0; j < 4; ++j) {
      int r = wr * 64 + mt * 16 + er + j;
      if (r < rows) {
        float* op = out + (size_t)(row0 + r) * NDIM + col0 + wc * 64 + (lane & 15);
#pragma unroll
        for (int nt = 0; nt < 4; ++nt) op[nt * 16] = acc[mt][nt][j];
      }
    }
  }
}

// ---------------- fallback: direct fp32, reg-staged ----------------
__global__ __launch_bounds__(256) void moe_gemm_f32(
    const float* __restrict__ x, const float* __restrict__ w,
    const int* __restrict__ ms, float* __restrict__ out) {
  __shared__ __align__(16) char As[128 * 64 * 2];
  __shared__ __align__(16) char Bs[128 * 64 * 2];
  int sizes[NEXP];
#pragma unroll
  for (int i = 0; i < NEXP; ++i) sizes[i] = ms[i];
  const int bt = blockIdx.y;
  int e = 0, row0 = 0, rows = 0, acc_t = 0, start = 0;
  bool found = false;
#pragma unroll
  for (int i = 0; i < NEXP; ++i) {
    int nt = (sizes[i] + 127) >> 7;
    if (!found && bt < acc_t + nt) {
      found = true; e = i;
      int tt = bt - acc_t;
      row0 = start + tt * 128;
      rows = minI(sizes[i] - tt * 128, 128);
    }
    acc_t += nt; start += sizes[i];
  }
  if (!found) return;
  const int tid = threadIdx.x;
  const int lane = tid & 63;
  const int wave = tid >> 6;
  const int wm = wave >> 1, wn = wave & 1;
  const int col0 = blockIdx.x * 128;
  const float* wbase = w + (size_t)e * (size_t)NDIM * KDIM;
  const int sr = tid >> 1;
  const int sh = tid & 1;
  const float* aptr = x + (size_t)(row0 + sr) * KDIM + sh * 32;
  const float* bptr = wbase + (size_t)(col0 + sr) * KDIM + sh * 32;
  const bool aval = (sr < rows);
  f32x4 acc[4][4];
  const f32x4 zero = {0.f, 0.f, 0.f, 0.f};
#pragma unroll
  for (int i = 0; i < 4; ++i)
#pragma unroll
    for (int j = 0; j < 4; ++j) acc[i][j] = zero;
  for (int kb = 0; kb < KDIM / 64; ++kb) {
    {
      float4 v[8];
      if (aval) {
        const float4* p = (const float4*)(aptr + kb * 64);
#pragma unroll
        for (int j = 0; j < 8; ++j) v[j] = p[j];
      } else {
#pragma unroll
        for (int j = 0; j < 8; ++j) v[j] = make_float4(0.f, 0.f, 0.f, 0.f);
      }
#pragma unroll
      for (int j = 0; j < 4; ++j) {
        bf16x8 c = cvt8(v[2 * j], v[2 * j + 1]);
        int chunk = (sh * 4 + j) ^ (sr & 7);
        *(bf16x8*)(As + sr * 128 + chunk * 16) = c;
      }
    }
    {
      const float4* p = (const float4*)(bptr + kb * 64);
      float4 u[8];
#pragma unroll
      for (int j = 0; j < 8; ++j) u[j] = p[j];
#pragma unroll
      for (int j = 0; j < 4; ++j) {
        bf16x8 c = cvt8(u[2 * j], u[2 * j + 1]);
        int chunk = (sh * 4 + j) ^ (sr & 7);
        *(bf16x8*)(Bs + sr * 128 + chunk * 16) = c;
      }
    }
    __syncthreads();
#pragma unroll
    for (int ks = 0; ks < 2; ++ks) {
      bf16x8 afr[4], bfv[4];
#pragma unroll
      for (int mt = 0; mt < 4; ++mt) {
        int r = wm * 64 + mt * 16 + (lane & 15);
        int chunk = (ks * 4 + (lane >> 4)) ^ (r & 7);
        afr[mt] = *(const bf16x8*)(As + r * 128 + chunk * 16);
      }
#pragma unroll
      for (int nt = 0; nt < 4; ++nt) {
        int r = wn * 64 + nt * 16 + (lane & 15);
        int chunk = (ks * 4 + (lane >> 4)) ^ (r & 7);
        bfv[nt] = *(const bf16x8*)(Bs + r * 128 + chunk * 16);
      }
#pragma unroll
      for (int mt = 0; mt < 4; ++mt)
#pragma unroll
        for (int nt = 0; nt < 4; ++nt)
          acc[mt][nt] = __builtin_amdgcn_mfma_f32_16x16x32_bf16(
              afr[mt], bfv[nt], acc[mt][nt], 0, 0, 0);
    }
    __syncthreads();
  }
#pragma unroll
  for (int mt = 0; mt < 4; ++mt) {
#pragma unroll
    for (int j = 0; j < 4; ++j) {
      int r = wm * 64 + mt * 16 + (lane >> 4) * 4 + j;
      if (r < rows) {
        float* op = out + (size_t)(row0 + r) * NDIM + col0 + wn * 64 + (lane & 15);
#pragma unroll
        for (int nt = 0; nt < 4; ++nt) op[nt * 16] = acc[mt][nt][j];
      }
    }
  }
}

extern "C" void kernel_launch(void* const* d_in, const int* in_sizes, int n_in,
                              void* d_out, int out_size, void* d_ws, size_t ws_size,
                              hipStream_t stream) {
  const float* x = (const float*)d_in[0];
  const float* w = (const float*)d_in[1];
  const int* ms = (const int*)d_in[2];
  float* out = (float*)d_out;
  const size_t nx = (size_t)M_TOTAL * KDIM;
  const size_t nw = (size_t)NEXP * NDIM * KDIM;
  const size_t need = (nx + nw) * sizeof(__hip_bfloat16);
  if (ws_size >= need) {
    __hip_bfloat16* xb = (__hip_bfloat16*)d_ws;
    __hip_bfloat16* wb = xb + nx;
    cvt_both<<<2048, 256, 0, stream>>>(x, w, (bf16x8*)xb, (bf16x8*)wb);
    moe_gemm_d3<<<dim3(NWG), dim3(512), 0, stream>>>(xb, wb, ms, out);
  } else {
    moe_gemm_f32<<<dim3(16, 135), dim3(256), 0, stream>>>(x, w, ms, out);
  }
}

// Round 8
// 248.435 us; speedup vs baseline: 1.0776x; 1.0776x over previous
//
#include <hip/hip_runtime.h>
#include <hip/hip_bf16.h>

#define M_TOTAL 16384
#define KDIM 2048
#define NDIM 2048
#define NEXP 8
#define BM 256
#define BN 256
#define BK 32
#define MAX_ROW_TILES 71  // 16384/256 + 7 boundary extras
#define NWG (MAX_ROW_TILES * 8)

typedef __attribute__((ext_vector_type(8))) __bf16 bf16x8;
typedef __attribute__((ext_vector_type(4))) float f32x4;

__device__ inline int minI(int a, int b) { return a < b ? a : b; }

__device__ inline bf16x8 cvt8(float4 a, float4 b) {
  bf16x8 r;
  r[0] = (__bf16)a.x; r[1] = (__bf16)a.y; r[2] = (__bf16)a.z; r[3] = (__bf16)a.w;
  r[4] = (__bf16)b.x; r[5] = (__bf16)b.y; r[6] = (__bf16)b.z; r[7] = (__bf16)b.w;
  return r;
}

__device__ inline void gload16(const void* g, void* l) {
  __builtin_amdgcn_global_load_lds(
      (const __attribute__((address_space(1))) void*)g,
      (__attribute__((address_space(3))) void*)l, 16, 0, 0);
}

// ---------------- fp32 -> bf16 conversion (x then W) ----------------
__global__ __launch_bounds__(256) void cvt_both(
    const float* __restrict__ x, const float* __restrict__ w,
    bf16x8* __restrict__ xb, bf16x8* __restrict__ wb) {
  const int NX = (M_TOTAL * KDIM) / 8;
  const int NW = (NEXP * NDIM * KDIM) / 8;
  const int stride = gridDim.x * blockDim.x;
  for (int i = blockIdx.x * blockDim.x + threadIdx.x; i < NX + NW; i += stride) {
    const float4* src = (i < NX) ? ((const float4*)x + (size_t)i * 2)
                                 : ((const float4*)w + (size_t)(i - NX) * 2);
    float4 a = src[0], b = src[1];
    bf16x8 c = cvt8(a, b);
    if (i < NX) xb[i] = c; else wb[i - NX] = c;
  }
}

// ---------------- grouped GEMM: 256x256, BK=32, 4 LDS buffers (128 KB),
// SINGLE barrier + SINGLE counted vmcnt(4) per K-tile. After the barrier each
// wave issues stage(t+2) + its 12 ds_reads + 32 MFMA and free-runs: the
// compiler's fine-grained lgkm waits start MFMA after the first frags land,
// so one wave's MFMA overlaps another wave's LDS reads (no collective
// LDS-window/MFMA-window alternation). Hazards:
//  RAW: reads(t) need buf staged at t-2: vmcnt(4)+barrier at tile t publishes.
//  WAR: stage(t+2) targets buffer whose readers (tile t-2) drained before
//       their MFMA issued, hence before they arrived at barrier(t).
// Swizzle (R4-verified, 0 conflicts): phys chunk = c ^ ((row>>1)&3), applied
// via pre-swizzled per-lane global source column; LDS dest stays linear.
__global__ __launch_bounds__(512, 2) void moe_gemm_sb(
    const __hip_bfloat16* __restrict__ xb, const __hip_bfloat16* __restrict__ wb,
    const int* __restrict__ ms, float* __restrict__ out) {
  __shared__ __align__(16) char lds[131072];

  // bijective XCD swizzle (NWG = 568 = 8*71)
  const int orig = blockIdx.x;
  const int wg = (orig & 7) * MAX_ROW_TILES + (orig >> 3);
  const int bt = wg >> 3;
  const int ntile = wg & 7;

  // ---- map bt -> (expert e, row0, rows) ----
  int sizes[NEXP];
#pragma unroll
  for (int i = 0; i < NEXP; ++i) sizes[i] = ms[i];
  int e = 0, row0 = 0, rows = 0, acc_t = 0, start = 0;
  bool found = false;
#pragma unroll
  for (int i = 0; i < NEXP; ++i) {
    int nt = (sizes[i] + BM - 1) >> 8;
    if (!found && bt < acc_t + nt) {
      found = true; e = i;
      int tt = bt - acc_t;
      row0 = start + tt * BM;
      rows = minI(sizes[i] - tt * BM, BM);
    }
    acc_t += nt; start += sizes[i];
  }
  if (!found) return;

  const int tid = threadIdx.x;
  const int lane = tid & 63;
  const int wave = tid >> 6;
  const int wr = wave >> 2, wc = wave & 3;  // 2x4 waves, 128x64 out each
  const int col0 = ntile * BN;

  // ---- staging: 4 units of 8KB per tile (A half0, A half1, B half0, B half1)
  // thread -> row rwh = wave*16 + lane>>2, phys chunk lane&3;
  // logical chunk = (lane&3)^((rwh>>1)&3) = (lane&3)^((lane>>3)&3).
  const int rwh = wave * 16 + (lane >> 2);
  const int colel = (((lane & 3) ^ ((lane >> 3) & 3)) << 3);
  const __hip_bfloat16* aS0 = xb + (size_t)minI(row0 + rwh, M_TOTAL - 1) * KDIM + colel;
  const __hip_bfloat16* aS1 = xb + (size_t)minI(row0 + 128 + rwh, M_TOTAL - 1) * KDIM + colel;
  const __hip_bfloat16* wbase = wb + (size_t)e * NDIM * KDIM;
  const __hip_bfloat16* bS0 = wbase + (size_t)(col0 + rwh) * KDIM + colel;
  const __hip_bfloat16* bS1 = wbase + (size_t)(col0 + 128 + rwh) * KDIM + colel;

  // ---- fragment read offsets (within a buffer), swizzled ----
  const int fr = lane & 15, fc = lane >> 4;
  const int laneOff = fr * 64 + ((fc ^ ((fr >> 1) & 3)) << 4);
  const int aOff = wr * 8192 + laneOff;
  const int bOff = 16384 + (wc >> 1) * 8192 + (wc & 1) * 4096 + laneOff;

  f32x4 acc[8][4];
  const f32x4 zero = {0.f, 0.f, 0.f, 0.f};
#pragma unroll
  for (int i = 0; i < 8; ++i)
#pragma unroll
    for (int j = 0; j < 4; ++j) acc[i][j] = zero;

#define ST4(BI, T) { char* b_ = lds + (BI) * 32768 + wave * 1024; \
    gload16(aS0 + (size_t)(T) * BK, b_); \
    gload16(aS1 + (size_t)(T) * BK, b_ + 8192); \
    gload16(bS0 + (size_t)(T) * BK, b_ + 16384); \
    gload16(bS1 + (size_t)(T) * BK, b_ + 24576); }
#define VM4 "vmcnt(4)"
#define VM0 "vmcnt(0)"

#define TILE(BI, T, DOST, VM) { \
    asm volatile("s_waitcnt " VM ::: "memory"); \
    __builtin_amdgcn_s_barrier(); \
    asm volatile("" ::: "memory"); \
    if (DOST) ST4(((BI) + 2) & 3, (T) + 2); \
    const char* bb_ = lds + (BI) * 32768; \
    bf16x8 af[8], bv[4]; \
    _Pragma("unroll") for (int mt = 0; mt < 8; ++mt) \
      af[mt] = *(const bf16x8*)(bb_ + aOff + mt * 1024); \
    _Pragma("unroll") for (int nt = 0; nt < 4; ++nt) \
      bv[nt] = *(const bf16x8*)(bb_ + bOff + nt * 1024); \
    __builtin_amdgcn_s_setprio(1); \
    _Pragma("unroll") for (int mt = 0; mt < 8; ++mt) \
      _Pragma("unroll") for (int nt = 0; nt < 4; ++nt) \
        acc[mt][nt] = __builtin_amdgcn_mfma_f32_16x16x32_bf16( \
            af[mt], bv[nt], acc[mt][nt], 0, 0, 0); \
    __builtin_amdgcn_s_setprio(0); \
  }

  // prologue: tiles 0,1 in flight (8 loads/thread)
  ST4(0, 0)
  ST4(1, 1)

  for (int i = 0; i < 15; ++i) {
    const int t = 4 * i;
    TILE(0, t,     true, VM4)
    TILE(1, t + 1, true, VM4)
    TILE(2, t + 2, true, VM4)
    TILE(3, t + 3, true, VM4)
  }
  TILE(0, 60, true,  VM4)
  TILE(1, 61, true,  VM4)
  TILE(2, 62, false, VM4)
  TILE(3, 63, false, VM0)

#undef TILE
#undef VM0
#undef VM4
#undef ST4

  // ---- epilogue: C/D layout col=lane&15, row=(lane>>4)*4+j ----
  const int er = (lane >> 4) * 4;
#pragma unroll
  for (int mt = 0; mt < 8; ++mt) {
#pragma unroll
    for (int j = 0; j < 4; ++j) {
      int r = wr * 128 + mt * 16 + er + j;
      if (r < rows) {
        float* op = out + (size_t)(row0 + r) * NDIM + col0 + wc * 64 + (lane & 15);
#pragma unroll
        for (int nt = 0; nt < 4; ++nt) op[nt * 16] = acc[mt][nt][j];
      }
    }
  }
}

// ---------------- fallback: direct fp32, reg-staged ----------------
__global__ __launch_bounds__(256) void moe_gemm_f32(
    const float* __restrict__ x, const float* __restrict__ w,
    const int* __restrict__ ms, float* __restrict__ out) {
  __shared__ __align__(16) char As[128 * 64 * 2];
  __shared__ __align__(16) char Bs[128 * 64 * 2];
  int sizes[NEXP];
#pragma unroll
  for (int i = 0; i < NEXP; ++i) sizes[i] = ms[i];
  const int bt = blockIdx.y;
  int e = 0, row0 = 0, rows = 0, acc_t = 0, start = 0;
  bool found = false;
#pragma unroll
  for (int i = 0; i < NEXP; ++i) {
    int nt = (sizes[i] + 127) >> 7;
    if (!found && bt < acc_t + nt) {
      found = true; e = i;
      int tt = bt - acc_t;
      row0 = start + tt * 128;
      rows = minI(sizes[i] - tt * 128, 128);
    }
    acc_t += nt; start += sizes[i];
  }
  if (!found) return;
  const int tid = threadIdx.x;
  const int lane = tid & 63;
  const int wave = tid >> 6;
  const int wm = wave >> 1, wn = wave & 1;
  const int col0 = blockIdx.x * 128;
  const float* wbase = w + (size_t)e * (size_t)NDIM * KDIM;
  const int sr = tid >> 1;
  const int sh = tid & 1;
  const float* aptr = x + (size_t)(row0 + sr) * KDIM + sh * 32;
  const float* bptr = wbase + (size_t)(col0 + sr) * KDIM + sh * 32;
  const bool aval = (sr < rows);
  f32x4 acc[4][4];
  const f32x4 zero = {0.f, 0.f, 0.f, 0.f};
#pragma unroll
  for (int i = 0; i < 4; ++i)
#pragma unroll
    for (int j = 0; j < 4; ++j) acc[i][j] = zero;
  for (int kb = 0; kb < KDIM / 64; ++kb) {
    {
      float4 v[8];
      if (aval) {
        const float4* p = (const float4*)(aptr + kb * 64);
#pragma unroll
        for (int j = 0; j < 8; ++j) v[j] = p[j];
      } else {
#pragma unroll
        for (int j = 0; j < 8; ++j) v[j] = make_float4(0.f, 0.f, 0.f, 0.f);
      }
#pragma unroll
      for (int j = 0; j < 4; ++j) {
        bf16x8 c = cvt8(v[2 * j], v[2 * j + 1]);
        int chunk = (sh * 4 + j) ^ (sr & 7);
        *(bf16x8*)(As + sr * 128 + chunk * 16) = c;
      }
    }
    {
      const float4* p = (const float4*)(bptr + kb * 64);
      float4 u[8];
#pragma unroll
      for (int j = 0; j < 8; ++j) u[j] = p[j];
#pragma unroll
      for (int j = 0; j < 4; ++j) {
        bf16x8 c = cvt8(u[2 * j], u[2 * j + 1]);
        int chunk = (sh * 4 + j) ^ (sr & 7);
        *(bf16x8*)(Bs + sr * 128 + chunk * 16) = c;
      }
    }
    __syncthreads();
#pragma unroll
    for (int ks = 0; ks < 2; ++ks) {
      bf16x8 afr[4], bfv[4];
#pragma unroll
      for (int mt = 0; mt < 4; ++mt) {
        int r = wm * 64 + mt * 16 + (lane & 15);
        int chunk = (ks * 4 + (lane >> 4)) ^ (r & 7);
        afr[mt] = *(const bf16x8*)(As + r * 128 + chunk * 16);
      }
#pragma unroll
      for (int nt = 0; nt < 4; ++nt) {
        int r = wn * 64 + nt * 16 + (lane & 15);
        int chunk = (ks * 4 + (lane >> 4)) ^ (r & 7);
        bfv[nt] = *(const bf16x8*)(Bs + r * 128 + chunk * 16);
      }
#pragma unroll
      for (int mt = 0; mt < 4; ++mt)
#pragma unroll
        for (int nt = 0; nt < 4; ++nt)
          acc[mt][nt] = __builtin_amdgcn_mfma_f32_16x16x32_bf16(
              afr[mt], bfv[nt], acc[mt][nt], 0, 0, 0);
    }
    __syncthreads();
  }
#pragma unroll
  for (int mt = 0; mt < 4; ++mt) {
#pragma unroll
    for (int j = 0; j < 4; ++j) {
      int r = wm * 64 + mt * 16 + (lane >> 4) * 4 + j;
      if (r < rows) {
        float* op = out + (size_t)(row0 + r) * NDIM + col0 + wn * 64 + (lane & 15);
#pragma unroll
        for (int nt = 0; nt < 4; ++nt) op[nt * 16] = acc[mt][nt][j];
      }
    }
  }
}

extern "C" void kernel_launch(void* const* d_in, const int* in_sizes, int n_in,
                              void* d_out, int out_size, void* d_ws, size_t ws_size,
                              hipStream_t stream) {
  const float* x = (const float*)d_in[0];
  const float* w = (const float*)d_in[1];
  const int* ms = (const int*)d_in[2];
  float* out = (float*)d_out;
  const size_t nx = (size_t)M_TOTAL * KDIM;
  const size_t nw = (size_t)NEXP * NDIM * KDIM;
  const size_t need = (nx + nw) * sizeof(__hip_bfloat16);
  if (ws_size >= need) {
    __hip_bfloat16* xb = (__hip_bfloat16*)d_ws;
    __hip_bfloat16* wb = xb + nx;
    cvt_both<<<2048, 256, 0, stream>>>(x, w, (bf16x8*)xb, (bf16x8*)wb);
    moe_gemm_sb<<<dim3(NWG), dim3(512), 0, stream>>>(xb, wb, ms, out);
  } else {
    moe_gemm_f32<<<dim3(16, 135), dim3(256), 0, stream>>>(x, w, ms, out);
  }
}

// Round 9
// 238.309 us; speedup vs baseline: 1.1234x; 1.0425x over previous
//
#include <hip/hip_runtime.h>
#include <hip/hip_bf16.h>

#define M_TOTAL 16384
#define KDIM 2048
#define NDIM 2048
#define NEXP 8
#define BM 256
#define BN 256
#define BK 64
#define MAX_ROW_TILES 71  // 16384/256 + 7 boundary extras
#define NWG (MAX_ROW_TILES * 8)

typedef __attribute__((ext_vector_type(8))) __bf16 bf16x8;
typedef __attribute__((ext_vector_type(4))) float f32x4;

__device__ inline int minI(int a, int b) { return a < b ? a : b; }

__device__ inline bf16x8 cvt8(float4 a, float4 b) {
  bf16x8 r;
  r[0] = (__bf16)a.x; r[1] = (__bf16)a.y; r[2] = (__bf16)a.z; r[3] = (__bf16)a.w;
  r[4] = (__bf16)b.x; r[5] = (__bf16)b.y; r[6] = (__bf16)b.z; r[7] = (__bf16)b.w;
  return r;
}

__device__ inline void gload16(const void* g, void* l) {
  __builtin_amdgcn_global_load_lds(
      (const __attribute__((address_space(1))) void*)g,
      (__attribute__((address_space(3))) void*)l, 16, 0, 0);
}

// ---------------- fp32 -> bf16 conversion (x then W) ----------------
__global__ __launch_bounds__(256) void cvt_both(
    const float* __restrict__ x, const float* __restrict__ w,
    bf16x8* __restrict__ xb, bf16x8* __restrict__ wb) {
  const int NX = (M_TOTAL * KDIM) / 8;
  const int NW = (NEXP * NDIM * KDIM) / 8;
  const int stride = gridDim.x * blockDim.x;
  for (int i = blockIdx.x * blockDim.x + threadIdx.x; i < NX + NW; i += stride) {
    const float4* src = (i < NX) ? ((const float4*)x + (size_t)i * 2)
                                 : ((const float4*)w + (size_t)(i - NX) * 2);
    float4 a = src[0], b = src[1];
    bf16x8 c = cvt8(a, b);
    if (i < NX) xb[i] = c; else wb[i - NX] = c;
  }
}

// ---------------- grouped GEMM: 256x256 tile, BK=64, 8-phase schedule.
// IDENTICAL to round-6 kernel except: NO memory clobbers on any s_waitcnt
// inline asm and NO empty asm fences. Rationale: SIInsertWaitcnts treats
// memory-clobbered inline asm as may-load/may-store and drains vmcnt+lgkmcnt
// to 0 before it -- every counted vmcnt(N) in rounds 3-8 was silently a full
// drain, degenerating all pipelines to the m97 drain-per-phase structure.
// The m201 template (refcheck'd) uses clobber-free waitcnt asm exactly so the
// counted waits survive; ds_reads stay ordered because they are compiler-
// visible LDS loads that alias the gload_lds LDS writes present in each phase.
__global__ __launch_bounds__(512, 2) void moe_gemm_8pnc(
    const __hip_bfloat16* __restrict__ xb, const __hip_bfloat16* __restrict__ wb,
    const int* __restrict__ ms, float* __restrict__ out) {
  __shared__ __align__(16) char lds[131072];

  // bijective XCD swizzle (NWG = 568 = 8*71)
  const int orig = blockIdx.x;
  const int wg = (orig & 7) * MAX_ROW_TILES + (orig >> 3);
  const int bt = wg >> 3;
  const int ntile = wg & 7;

  // ---- map bt -> (expert e, row0, rows) ----
  int sizes[NEXP];
#pragma unroll
  for (int i = 0; i < NEXP; ++i) sizes[i] = ms[i];
  int e = 0, row0 = 0, rows = 0, acc_t = 0, start = 0;
  bool found = false;
#pragma unroll
  for (int i = 0; i < NEXP; ++i) {
    int nt = (sizes[i] + BM - 1) >> 8;
    if (!found && bt < acc_t + nt) {
      found = true; e = i;
      int tt = bt - acc_t;
      row0 = start + tt * BM;
      rows = minI(sizes[i] - tt * BM, BM);
    }
    acc_t += nt; start += sizes[i];
  }
  if (!found) return;

  const int tid = threadIdx.x;
  const int lane = tid & 63;
  const int wave = tid >> 6;
  const int wr = wave >> 2, wc = wave & 3;  // 2x4 waves, 128x64 out each
  const int col0 = ntile * BN;

  // ---- staging thread coords: unit = 64 rows x 128B; thread t -> row t>>3,
  // phys chunk t&7; logical chunk = (t&7)^(row&7) -> pre-swizzled source col.
  const int urow = tid >> 3;
  const int colel = (((tid & 7) ^ ((tid >> 3) & 7)) << 3);
  const __hip_bfloat16* wbase = wb + (size_t)e * NDIM * KDIM;
  const __hip_bfloat16* aP00 = xb + (size_t)minI(row0 +   0 + urow, M_TOTAL - 1) * KDIM + colel;
  const __hip_bfloat16* aP01 = xb + (size_t)minI(row0 +  64 + urow, M_TOTAL - 1) * KDIM + colel;
  const __hip_bfloat16* aP10 = xb + (size_t)minI(row0 + 128 + urow, M_TOTAL - 1) * KDIM + colel;
  const __hip_bfloat16* aP11 = xb + (size_t)minI(row0 + 192 + urow, M_TOTAL - 1) * KDIM + colel;
  const __hip_bfloat16* bP0 = wbase + (size_t)(col0 +   0 + urow) * KDIM + colel;
  const __hip_bfloat16* bP1 = wbase + (size_t)(col0 +  64 + urow) * KDIM + colel;
  const __hip_bfloat16* bP2 = wbase + (size_t)(col0 + 128 + urow) * KDIM + colel;
  const __hip_bfloat16* bP3 = wbase + (size_t)(col0 + 192 + urow) * KDIM + colel;

  // ---- fragment read lane terms (swizzled; phys = (ks*4+fc) ^ (fr&7)) ----
  const int fr = lane & 15, fc = lane >> 4;
  const int swz0 = fr * 128 + (((fc) ^ (fr & 7)) << 4);      // ks=0
  const int swz1 = fr * 128 + (((4 + fc) ^ (fr & 7)) << 4);  // ks=1
  const int aBase = wr * 16384;
  const int bBase = 32768 + (wc >> 1) * 16384 + (wc & 1) * 8192;

  f32x4 acc[8][4];
  const f32x4 zero = {0.f, 0.f, 0.f, 0.f};
#pragma unroll
  for (int i = 0; i < 8; ++i)
#pragma unroll
    for (int j = 0; j < 4; ++j) acc[i][j] = zero;

  bf16x8 af[4], bv[4];

#define ST_A(D, H, L, KK) gload16(aP##H##L + (size_t)(KK) * BK, \
    lds + (D) * 65536 + ((H) * 2 + (L)) * 8192 + wave * 1024);
#define ST_B(D, Q, KK) gload16(bP##Q + (size_t)(KK) * BK, \
    lds + (D) * 65536 + 32768 + (Q) * 8192 + wave * 1024);
#define VM4 asm volatile("s_waitcnt vmcnt(4)");
#define VM2 asm volatile("s_waitcnt vmcnt(2)");
#define VM0 asm volatile("s_waitcnt vmcnt(0)");

#define PHASE(D, MH, SWZ, LOADB, STAGEBLK, WAITBLK) { \
    _Pragma("unroll") for (int mt = 0; mt < 4; ++mt) \
      af[mt] = *(const bf16x8*)(lds + (D) * 65536 + aBase + ((MH) * 4 + mt) * 2048 + SWZ); \
    if (LOADB) { _Pragma("unroll") for (int nt = 0; nt < 4; ++nt) \
      bv[nt] = *(const bf16x8*)(lds + (D) * 65536 + bBase + nt * 2048 + SWZ); } \
    STAGEBLK \
    __builtin_amdgcn_s_barrier(); \
    asm volatile("s_waitcnt lgkmcnt(0)"); \
    __builtin_amdgcn_s_setprio(1); \
    _Pragma("unroll") for (int mt = 0; mt < 4; ++mt) \
      _Pragma("unroll") for (int nt = 0; nt < 4; ++nt) \
        acc[(MH) * 4 + mt][nt] = __builtin_amdgcn_mfma_f32_16x16x32_bf16( \
            af[mt], bv[nt], acc[(MH) * 4 + mt][nt], 0, 0, 0); \
    __builtin_amdgcn_s_setprio(0); \
    WAITBLK \
    __builtin_amdgcn_s_barrier(); \
  }

  // ---- prologue: K0 fully (B0-3, AL, AH) + K1 B01 = 10 units; vmcnt(4)
  // leaves [K0 AH x2, K1 B01 x2] = exact steady-state carry-in. ----
  ST_B(0, 0, 0) ST_B(0, 1, 0) ST_B(0, 2, 0) ST_B(0, 3, 0)
  ST_A(0, 0, 0, 0) ST_A(0, 1, 0, 0)   // AL: local rows 0-63 of each half
  ST_A(0, 0, 1, 0) ST_A(0, 1, 1, 0)   // AH: local rows 64-127
  ST_B(1, 0, 1) ST_B(1, 1, 1)
  VM4
  __builtin_amdgcn_s_barrier();

  for (int i = 0; i < 15; ++i) {
    const int t = 2 * i;
    PHASE(0, 0, swz0, true,  { ST_B(1, 2, t + 1) ST_B(1, 3, t + 1) }, VM4)
    PHASE(0, 1, swz0, false, { ST_A(1, 0, 0, t + 1) ST_A(1, 1, 0, t + 1) }, )
    PHASE(0, 0, swz1, true,  { ST_A(1, 0, 1, t + 1) ST_A(1, 1, 1, t + 1) }, )
    PHASE(0, 1, swz1, false, { ST_B(0, 0, t + 2) ST_B(0, 1, t + 2) }, VM4)
    PHASE(1, 0, swz0, true,  { ST_B(0, 2, t + 2) ST_B(0, 3, t + 2) }, VM4)
    PHASE(1, 1, swz0, false, { ST_A(0, 0, 0, t + 2) ST_A(0, 1, 0, t + 2) }, )
    PHASE(1, 0, swz1, true,  { ST_A(0, 0, 1, t + 2) ST_A(0, 1, 1, t + 2) }, )
    PHASE(1, 1, swz1, false, { ST_B(1, 0, t + 3) ST_B(1, 1, t + 3) }, VM4)
  }
  // ---- peeled last iteration (t=30): finish staging K31, drain 4/2/0 ----
  PHASE(0, 0, swz0, true,  { ST_B(1, 2, 31) ST_B(1, 3, 31) }, VM4)
  PHASE(0, 1, swz0, false, { ST_A(1, 0, 0, 31) ST_A(1, 1, 0, 31) }, )
  PHASE(0, 0, swz1, true,  { ST_A(1, 0, 1, 31) ST_A(1, 1, 1, 31) }, )
  PHASE(0, 1, swz1, false, { }, VM2)
  PHASE(1, 0, swz0, true,  { }, VM0)
  PHASE(1, 1, swz0, false, { }, )
  PHASE(1, 0, swz1, true,  { }, )
  PHASE(1, 1, swz1, false, { }, )

#undef PHASE
#undef VM0
#undef VM2
#undef VM4
#undef ST_B
#undef ST_A

  // ---- epilogue: C/D layout col=lane&15, row=(lane>>4)*4+j ----
  const int er = (lane >> 4) * 4;
#pragma unroll
  for (int mt = 0; mt < 8; ++mt) {
#pragma unroll
    for (int j = 0; j < 4; ++j) {
      int r = wr * 128 + mt * 16 + er + j;
      if (r < rows) {
        float* op = out + (size_t)(row0 + r) * NDIM + col0 + wc * 64 + (lane & 15);
#pragma unroll
        for (int nt = 0; nt < 4; ++nt) op[nt * 16] = acc[mt][nt][j];
      }
    }
  }
}

// ---------------- fallback: direct fp32, reg-staged ----------------
__global__ __launch_bounds__(256) void moe_gemm_f32(
    const float* __restrict__ x, const float* __restrict__ w,
    const int* __restrict__ ms, float* __restrict__ out) {
  __shared__ __align__(16) char As[128 * 64 * 2];
  __shared__ __align__(16) char Bs[128 * 64 * 2];
  int sizes[NEXP];
#pragma unroll
  for (int i = 0; i < NEXP; ++i) sizes[i] = ms[i];
  const int bt = blockIdx.y;
  int e = 0, row0 = 0, rows = 0, acc_t = 0, start = 0;
  bool found = false;
#pragma unroll
  for (int i = 0; i < NEXP; ++i) {
    int nt = (sizes[i] + 127) >> 7;
    if (!found && bt < acc_t + nt) {
      found = true; e = i;
      int tt = bt - acc_t;
      row0 = start + tt * 128;
      rows = minI(sizes[i] - tt * 128, 128);
    }
    acc_t += nt; start += sizes[i];
  }
  if (!found) return;
  const int tid = threadIdx.x;
  const int lane = tid & 63;
  const int wave = tid >> 6;
  const int wm = wave >> 1, wn = wave & 1;
  const int col0 = blockIdx.x * 128;
  const float* wbase = w + (size_t)e * (size_t)NDIM * KDIM;
  const int sr = tid >> 1;
  const int sh = tid & 1;
  const float* aptr = x + (size_t)(row0 + sr) * KDIM + sh * 32;
  const float* bptr = wbase + (size_t)(col0 + sr) * KDIM + sh * 32;
  const bool aval = (sr < rows);
  f32x4 acc[4][4];
  const f32x4 zero = {0.f, 0.f, 0.f, 0.f};
#pragma unroll
  for (int i = 0; i < 4; ++i)
#pragma unroll
    for (int j = 0; j < 4; ++j) acc[i][j] = zero;
  for (int kb = 0; kb < KDIM / 64; ++kb) {
    {
      float4 v[8];
      if (aval) {
        const float4* p = (const float4*)(aptr + kb * 64);
#pragma unroll
        for (int j = 0; j < 8; ++j) v[j] = p[j];
      } else {
#pragma unroll
        for (int j = 0; j < 8; ++j) v[j] = make_float4(0.f, 0.f, 0.f, 0.f);
      }
#pragma unroll
      for (int j = 0; j < 4; ++j) {
        bf16x8 c = cvt8(v[2 * j], v[2 * j + 1]);
        int chunk = (sh * 4 + j) ^ (sr & 7);
        *(bf16x8*)(As + sr * 128 + chunk * 16) = c;
      }
    }
    {
      const float4* p = (const float4*)(bptr + kb * 64);
      float4 u[8];
#pragma unroll
      for (int j = 0; j < 8; ++j) u[j] = p[j];
#pragma unroll
      for (int j = 0; j < 4; ++j) {
        bf16x8 c = cvt8(u[2 * j], u[2 * j + 1]);
        int chunk = (sh * 4 + j) ^ (sr & 7);
        *(bf16x8*)(Bs + sr * 128 + chunk * 16) = c;
      }
    }
    __syncthreads();
#pragma unroll
    for (int ks = 0; ks < 2; ++ks) {
      bf16x8 afr[4], bfv[4];
#pragma unroll
      for (int mt = 0; mt < 4; ++mt) {
        int r = wm * 64 + mt * 16 + (lane & 15);
        int chunk = (ks * 4 + (lane >> 4)) ^ (r & 7);
        afr[mt] = *(const bf16x8*)(As + r * 128 + chunk * 16);
      }
#pragma unroll
      for (int nt = 0; nt < 4; ++nt) {
        int r = wn * 64 + nt * 16 + (lane & 15);
        int chunk = (ks * 4 + (lane >> 4)) ^ (r & 7);
        bfv[nt] = *(const bf16x8*)(Bs + r * 128 + chunk * 16);
      }
#pragma unroll
      for (int mt = 0; mt < 4; ++mt)
#pragma unroll
        for (int nt = 0; nt < 4; ++nt)
          acc[mt][nt] = __builtin_amdgcn_mfma_f32_16x16x32_bf16(
              afr[mt], bfv[nt], acc[mt][nt], 0, 0, 0);
    }
    __syncthreads();
  }
#pragma unroll
  for (int mt = 0; mt < 4; ++mt) {
#pragma unroll
    for (int j = 0; j < 4; ++j) {
      int r = wm * 64 + mt * 16 + (lane >> 4) * 4 + j;
      if (r < rows) {
        float* op = out + (size_t)(row0 + r) * NDIM + col0 + wn * 64 + (lane & 15);
#pragma unroll
        for (int nt = 0; nt < 4; ++nt) op[nt * 16] = acc[mt][nt][j];
      }
    }
  }
}

extern "C" void kernel_launch(void* const* d_in, const int* in_sizes, int n_in,
                              void* d_out, int out_size, void* d_ws, size_t ws_size,
                              hipStream_t stream) {
  const float* x = (const float*)d_in[0];
  const float* w = (const float*)d_in[1];
  const int* ms = (const int*)d_in[2];
  float* out = (float*)d_out;
  const size_t nx = (size_t)M_TOTAL * KDIM;
  const size_t nw = (size_t)NEXP * NDIM * KDIM;
  const size_t need = (nx + nw) * sizeof(__hip_bfloat16);
  if (ws_size >= need) {
    __hip_bfloat16* xb = (__hip_bfloat16*)d_ws;
    __hip_bfloat16* wb = xb + nx;
    cvt_both<<<2048, 256, 0, stream>>>(x, w, (bf16x8*)xb, (bf16x8*)wb);
    moe_gemm_8pnc<<<dim3(NWG), dim3(512), 0, stream>>>(xb, wb, ms, out);
  } else {
    moe_gemm_f32<<<dim3(16, 135), dim3(256), 0, stream>>>(x, w, ms, out);
  }
}